// Round 2
// baseline (665.175 us; speedup 1.0000x reference)
//
#include <hip/hip_runtime.h>
#include <math.h>

// GCN 2-layer + pool + head, gather formulation (CSR by destination).
//
// Workspace (4B units):
//   cnt    : N      incoming-edge count per node (int)
//   start  : N      CSR segment start per node (int, unordered segments)
//   cur    : N      fill cursor per node (int)
//   cursor : 1      global segment allocator (int)
//   dinv   : N      rsqrt(deg) incl self-loop (float)
//   eidx   : E      CSR edge source indices (int)
//   h0     : 16N    x@W1 (float); ALIASED as t2 = h1@W2 after gather1
//   h1     : 16N    layer-1 output (float)
//   g      : 16G    pooled graph features (float)
// Total = 36N + E + 16G + 1 floats ~= 27.3 MB.

#define TB 256

__global__ void k_init(int* cnt, int* cur, int* cursor, float* g, int N, int G16) {
    int i = blockIdx.x * blockDim.x + threadIdx.x;
    if (i < N) { cnt[i] = 0; cur[i] = 0; }
    if (i < G16) g[i] = 0.0f;
    if (i == 0) *cursor = 0;
}

__global__ void k_count(const int* __restrict__ col, int* cnt, int E) {
    int e = blockIdx.x * blockDim.x + threadIdx.x;
    if (e < E) atomicAdd(&cnt[col[e]], 1);
}

// Wave-aggregated segment allocation: one atomic per wave, not per node.
// Segment order across nodes is arbitrary — CSR only needs disjointness.
// Also computes dinv = rsqrt(deg) with deg = cnt + 1 (self-loop).
__global__ void k_alloc(const int* __restrict__ cnt, int* start, float* dinv,
                        int* cursor, int N) {
    int v = blockIdx.x * blockDim.x + threadIdx.x;
    int lane = threadIdx.x & 63;
    int c = (v < N) ? cnt[v] : 0;
    int incl = c;
#pragma unroll
    for (int d = 1; d < 64; d <<= 1) {
        int t = __shfl_up(incl, d, 64);
        if (lane >= d) incl += t;
    }
    int total = __shfl(incl, 63, 64);
    int base = 0;
    if (lane == 63) base = atomicAdd(cursor, total);
    base = __shfl(base, 63, 64);
    if (v < N) {
        start[v] = base + incl - c;
        dinv[v] = rsqrtf((float)(c + 1));
    }
}

// h0[v][k] = sum_c x[v][c] * W1[c][k]   (W1 is 3x16 row-major)
__global__ void k_xw1(const float* __restrict__ x, const float* __restrict__ W1,
                      float* __restrict__ h0, int N) {
    int t = blockIdx.x * blockDim.x + threadIdx.x;
    if (t >= N * 16) return;
    int v = t >> 4, k = t & 15;
    float x0 = x[v * 3 + 0], x1 = x[v * 3 + 1], x2 = x[v * 3 + 2];
    h0[t] = x0 * W1[k] + x1 * W1[16 + k] + x2 * W1[32 + k];
}

__global__ void k_fill(const int* __restrict__ row, const int* __restrict__ col,
                       const int* __restrict__ start, int* cur, int* eidx, int E) {
    int e = blockIdx.x * blockDim.x + threadIdx.x;
    if (e >= E) return;
    int c = col[e];
    int p = start[c] + atomicAdd(&cur[c], 1);
    eidx[p] = row[e];
}

// One wave per node. Lane layout: k = lane&15 (feature), slot = lane>>4
// (edge sub-slot, 4 edges in flight per wave iteration).
// MODE 0: dst[v] = relu(sum + selfloop + bias)
// MODE 1: g[batch[v]] += (sum + selfloop + bias)   (atomic pool)
template<int MODE>
__global__ void k_gather(const int* __restrict__ start, const int* __restrict__ cnt,
                         const int* __restrict__ eidx, const float* __restrict__ dinv,
                         const float* __restrict__ src, const float* __restrict__ bias,
                         const int* __restrict__ batch, float* __restrict__ dst, int N) {
    int wid = (blockIdx.x * blockDim.x + threadIdx.x) >> 6;
    if (wid >= N) return;
    int lane = threadIdx.x & 63;
    int k = lane & 15, slot = lane >> 4;
    int s = start[wid];
    int n = cnt[wid];
    float dv = dinv[wid];
    float acc = 0.0f;
    for (int p = slot; p < n; p += 4) {
        int r = eidx[s + p];
        acc += dinv[r] * src[r * 16 + k];
    }
    // reduce the 4 edge sub-slots (lanes k, k+16, k+32, k+48)
    acc += __shfl_xor(acc, 16, 64);
    acc += __shfl_xor(acc, 32, 64);
    if (lane < 16) {
        float val = dv * acc + dv * dv * src[wid * 16 + k] + bias[k];
        if (MODE == 0) {
            dst[wid * 16 + k] = fmaxf(val, 0.0f);
        } else {
            atomicAdd(&dst[batch[wid] * 16 + k], val);
        }
    }
}

// t2[v][k] = sum_j h1[v][j] * W2[j][k]   (W2 16x16 row-major, staged in LDS)
__global__ void k_hw2(const float* __restrict__ h1, const float* __restrict__ W2,
                      float* __restrict__ t2, int N) {
    __shared__ float sW[256];
    if (threadIdx.x < 256) sW[threadIdx.x] = W2[threadIdx.x];
    __syncthreads();
    int t = blockIdx.x * blockDim.x + threadIdx.x;
    if (t >= N * 16) return;
    int v = t >> 4, k = t & 15;
    const float* hr = h1 + v * 16;
    float acc = 0.0f;
#pragma unroll
    for (int j = 0; j < 16; ++j) acc += hr[j] * sW[j * 16 + k];
    t2[t] = acc;
}

// logits = g @ Wl + bl (16x7), then log_softmax over 7. One thread per graph.
__global__ void k_head(const float* __restrict__ g, const float* __restrict__ Wl,
                       const float* __restrict__ bl, float* __restrict__ out, int G) {
    int gi = blockIdx.x * blockDim.x + threadIdx.x;
    if (gi >= G) return;
    float gv[16];
#pragma unroll
    for (int k = 0; k < 16; ++k) gv[k] = g[gi * 16 + k];
    float lo[7];
    float mx = -1e30f;
#pragma unroll
    for (int j = 0; j < 7; ++j) {
        float a = bl[j];
#pragma unroll
        for (int k = 0; k < 16; ++k) a += gv[k] * Wl[k * 7 + j];
        lo[j] = a;
        mx = fmaxf(mx, a);
    }
    float s = 0.0f;
#pragma unroll
    for (int j = 0; j < 7; ++j) s += expf(lo[j] - mx);
    float lse = mx + logf(s);
#pragma unroll
    for (int j = 0; j < 7; ++j) out[gi * 7 + j] = lo[j] - lse;
}

extern "C" void kernel_launch(void* const* d_in, const int* in_sizes, int n_in,
                              void* d_out, int out_size, void* d_ws, size_t ws_size,
                              hipStream_t stream) {
    const float* x     = (const float*)d_in[0];
    const int*   ei    = (const int*)d_in[1];   // row = ei[0:E), col = ei[E:2E)
    const int*   batch = (const int*)d_in[3];
    const float* W1 = (const float*)d_in[4];
    const float* b1 = (const float*)d_in[5];
    const float* W2 = (const float*)d_in[6];
    const float* b2 = (const float*)d_in[7];
    const float* Wl = (const float*)d_in[8];
    const float* bl = (const float*)d_in[9];
    float* out = (float*)d_out;

    const int N = in_sizes[0] / 3;
    const int E = in_sizes[1] / 2;
    const int G = out_size / 7;

    const int* row = ei;
    const int* col = ei + E;

    int*   cnt    = (int*)d_ws;           // N
    int*   start  = cnt + N;              // N
    int*   cur    = start + N;            // N
    int*   cursor = cur + N;              // 1
    float* dinv   = (float*)(cursor + 1); // N
    int*   eidx   = (int*)(dinv + N);     // E
    float* h0     = (float*)(eidx + E);   // 16N
    float* h1     = h0 + 16 * N;          // 16N
    float* t2     = h0;                   // alias: h0 dead after gather1
    float* g      = h1 + 16 * N;          // 16G

    const int n16 = N * 16;

    k_init<<<(N + TB - 1) / TB, TB, 0, stream>>>(cnt, cur, cursor, g, N, G * 16);
    k_count<<<(E + TB - 1) / TB, TB, 0, stream>>>(col, cnt, E);
    k_alloc<<<(N + TB - 1) / TB, TB, 0, stream>>>(cnt, start, dinv, cursor, N);
    k_xw1<<<(n16 + TB - 1) / TB, TB, 0, stream>>>(x, W1, h0, N);
    k_fill<<<(E + TB - 1) / TB, TB, 0, stream>>>(row, col, start, cur, eidx, E);
    // 4 waves (= 4 nodes) per 256-thread block
    k_gather<0><<<(N + 3) / 4, TB, 0, stream>>>(start, cnt, eidx, dinv, h0, b1, batch, h1, N);
    k_hw2<<<(n16 + TB - 1) / TB, TB, 0, stream>>>(h1, W2, t2, N);
    k_gather<1><<<(N + 3) / 4, TB, 0, stream>>>(start, cnt, eidx, dinv, t2, b2, batch, g, N);
    k_head<<<(G + TB - 1) / TB, TB, 0, stream>>>(g, Wl, bl, out, G);
}